// Round 1
// baseline (5297.398 us; speedup 1.0000x reference)
//
#include <hip/hip_runtime.h>
#include <hip/hip_bf16.h>
#include <math.h>

// Problem constants (from reference): N=50000, D=64, E=800000, H=64
#define DFEAT 64

// ---------------- count in-degree ----------------
__global__ void count_edges_k(const int* __restrict__ rows, int E, int* __restrict__ cnt) {
    int e = blockIdx.x * blockDim.x + threadIdx.x;
    if (e < E) atomicAdd(&cnt[rows[e]], 1);
}

// cntf[i] = (float)max(cnt[i],1)   (covers both pos+neg arrays in one launch)
__global__ void make_cntf_k(const int* __restrict__ cnt, int n2, float* __restrict__ cntf) {
    int i = blockIdx.x * blockDim.x + threadIdx.x;
    if (i < n2) cntf[i] = (float)(cnt[i] > 1 ? cnt[i] : 1);
}

// ---------------- scatter-add: acc[rows[e]] += src[cols[e]] ----------------
// 16 lanes per edge, each lane handles 4 floats (float4 gather + 4 atomics)
__global__ void scatter_add_k(const float* __restrict__ src, const int* __restrict__ rows,
                              const int* __restrict__ cols, int E, float* __restrict__ acc) {
    int t = blockIdx.x * blockDim.x + threadIdx.x;
    int e = t >> 4;
    if (e >= E) return;
    int q = (t & 15) << 2;
    int r = rows[e], c = cols[e];
    float4 v = *reinterpret_cast<const float4*>(src + (size_t)c * DFEAT + q);
    float* dst = acc + (size_t)r * DFEAT + q;
    atomicAdd(dst + 0, v.x);
    atomicAdd(dst + 1, v.y);
    atomicAdd(dst + 2, v.z);
    atomicAdd(dst + 3, v.w);
}

// ---------------- fused: out = tanh(l2norm(concat @ W + b)) ----------------
// One wave per node row; lane = output column h (H=64 == wave size).
// W transposed into LDS with stride K+4 (lane stride = 4 banks -> conflict-free b128).
template<int K, bool HAS2>
__global__ __launch_bounds__(256) void fused_linear_k(
        const float* __restrict__ p1, const float* __restrict__ c1,
        const float* __restrict__ p2, const float* __restrict__ c2,
        const float* __restrict__ p3,
        const float* __restrict__ W, const float* __restrict__ b,
        float* __restrict__ out, int out_stride) {
    constexpr int KP = K + 4;
    __shared__ float Wt[64 * KP];
    __shared__ float bs[64];
    __shared__ float cat[4][K];

    for (int idx = threadIdx.x; idx < K * 64; idx += 256) {
        int k = idx >> 6, h = idx & 63;
        Wt[h * KP + k] = W[idx];          // W is [K,64] row-major
    }
    if (threadIdx.x < 64) bs[threadIdx.x] = b[threadIdx.x];

    int wave = threadIdx.x >> 6;
    int lane = threadIdx.x & 63;
    int row  = blockIdx.x * 4 + wave;      // grid sized exactly: n % 4 == 0

    float d1 = c1[row];
    cat[wave][lane] = p1[(size_t)row * 64 + lane] / d1;
    if (HAS2) {
        float d2 = c2[row];
        cat[wave][64 + lane]  = p2[(size_t)row * 64 + lane] / d2;
        cat[wave][128 + lane] = p3[(size_t)row * 64 + lane];
    } else {
        cat[wave][64 + lane]  = p3[(size_t)row * 64 + lane];
    }
    __syncthreads();

    const float* wrow = &Wt[lane * KP];
    float acc = 0.f;
    #pragma unroll 8
    for (int k = 0; k < K; k += 4) {
        float4 cv = *reinterpret_cast<const float4*>(&cat[wave][k]);  // broadcast
        float4 wv = *reinterpret_cast<const float4*>(&wrow[k]);
        acc = fmaf(cv.x, wv.x, acc);
        acc = fmaf(cv.y, wv.y, acc);
        acc = fmaf(cv.z, wv.z, acc);
        acc = fmaf(cv.w, wv.w, acc);
    }
    float v = acc + bs[lane];
    float ss = v * v;
    #pragma unroll
    for (int i = 1; i < 64; i <<= 1) ss += __shfl_xor(ss, i);
    float denom = fmaxf(sqrtf(ss), 1e-12f);
    out[(size_t)row * out_stride + lane] = tanhf(v / denom);
}

// ---------------- logits + log_softmax + argmax + node norm ----------------
__global__ __launch_bounds__(256) void logits_k(
        const float* __restrict__ z, const float* __restrict__ Wr,
        const float* __restrict__ br, const int* __restrict__ comm,
        float* __restrict__ clar_f, int* __restrict__ clar_i,
        float* __restrict__ invn, float* __restrict__ lp_sum, int n) {
    __shared__ float Wl[128 * 3];
    for (int idx = threadIdx.x; idx < 384; idx += blockDim.x) Wl[idx] = Wr[idx];
    __syncthreads();
    int i = blockIdx.x * blockDim.x + threadIdx.x;
    float lp = 0.f;
    if (i < n) {
        float l0 = br[0], l1 = br[1], l2 = br[2], ss = 0.f;
        const float* zr = z + (size_t)i * 128;
        #pragma unroll 4
        for (int k = 0; k < 128; k += 4) {
            float4 v = *reinterpret_cast<const float4*>(zr + k);
            float zz[4] = {v.x, v.y, v.z, v.w};
            #pragma unroll
            for (int j = 0; j < 4; ++j) {
                float zv = zz[j];
                int kk = k + j;
                l0 = fmaf(zv, Wl[3 * kk + 0], l0);
                l1 = fmaf(zv, Wl[3 * kk + 1], l1);
                l2 = fmaf(zv, Wl[3 * kk + 2], l2);
                ss = fmaf(zv, zv, ss);
            }
        }
        invn[i] = 1.f / fmaxf(sqrtf(ss), 1e-8f);
        int idx = 0; float mv = l0;
        if (l1 > mv) { mv = l1; idx = 1; }
        if (l2 > mv) { mv = l2; idx = 2; }
        clar_i[i] = idx;
        clar_f[i] = (float)idx;
        float lse = mv + logf(expf(l0 - mv) + expf(l1 - mv) + expf(l2 - mv));
        int c = comm[i];
        lp = (c == 0 ? l0 : (c == 1 ? l1 : l2)) - lse;
    }
    #pragma unroll
    for (int o = 1; o < 64; o <<= 1) lp += __shfl_xor(lp, o);
    __shared__ float wsum[4];
    if ((threadIdx.x & 63) == 0) wsum[threadIdx.x >> 6] = lp;
    __syncthreads();
    if (threadIdx.x == 0) atomicAdd(lp_sum, wsum[0] + wsum[1] + wsum[2] + wsum[3]);
}

// ---------------- cosine-sim edge losses ----------------
// 8 lanes per edge; MODE 0: sum max(cos,0) where clarify differs (pos edges)
//                  MODE 1: sum -min(cos,0) where clarify equal (neg edges)
template<int MODE>
__global__ __launch_bounds__(256) void sim_k(
        const float* __restrict__ z, const float* __restrict__ invn,
        const int* __restrict__ clar, const int* __restrict__ ri,
        const int* __restrict__ ci, int E, float* __restrict__ osum) {
    int t = blockIdx.x * blockDim.x + threadIdx.x;
    int e = t >> 3;
    int sub = t & 7;
    float contrib = 0.f;
    if (e < E) {
        int a = ri[e], b = ci[e];
        const float* za = z + (size_t)a * 128 + sub * 16;
        const float* zb = z + (size_t)b * 128 + sub * 16;
        float d = 0.f;
        #pragma unroll
        for (int q = 0; q < 16; q += 4) {
            float4 x = *reinterpret_cast<const float4*>(za + q);
            float4 y = *reinterpret_cast<const float4*>(zb + q);
            d = fmaf(x.x, y.x, d);
            d = fmaf(x.y, y.y, d);
            d = fmaf(x.z, y.z, d);
            d = fmaf(x.w, y.w, d);
        }
        d += __shfl_xor(d, 1);
        d += __shfl_xor(d, 2);
        d += __shfl_xor(d, 4);
        if (sub == 0) {
            float cosv = d * invn[a] * invn[b];
            if (MODE == 0) { if (clar[a] != clar[b]) contrib = fmaxf(cosv, 0.f); }
            else           { if (clar[a] == clar[b]) contrib = -fminf(cosv, 0.f); }
        }
    }
    #pragma unroll
    for (int o = 1; o < 64; o <<= 1) contrib += __shfl_xor(contrib, o);
    __shared__ float wsum[4];
    if ((threadIdx.x & 63) == 0) wsum[threadIdx.x >> 6] = contrib;
    __syncthreads();
    if (threadIdx.x == 0) atomicAdd(osum, wsum[0] + wsum[1] + wsum[2] + wsum[3]);
}

__global__ void finalize_k(const float* __restrict__ scal, float* __restrict__ out,
                           int n, int E) {
    if (threadIdx.x == 0 && blockIdx.x == 0) {
        float reg_loss = -scal[0] / (float)n;
        float sim1 = scal[1] / (float)E;
        float sim2 = scal[2] / (float)E;
        out[0] = 0.8f * reg_loss + 0.2f * (sim1 + sim2);
    }
}

extern "C" void kernel_launch(void* const* d_in, const int* in_sizes, int n_in,
                              void* d_out, int out_size, void* d_ws, size_t ws_size,
                              hipStream_t stream) {
    const float* X   = (const float*)d_in[0];
    const float* pbW = (const float*)d_in[1];
    const float* pbB = (const float*)d_in[2];
    const float* nbW = (const float*)d_in[3];
    const float* nbB = (const float*)d_in[4];
    const float* pdW = (const float*)d_in[5];
    const float* pdB = (const float*)d_in[6];
    const float* ndW = (const float*)d_in[7];
    const float* ndB = (const float*)d_in[8];
    const float* rW  = (const float*)d_in[9];
    const float* rB  = (const float*)d_in[10];
    const int* pe    = (const int*)d_in[11];
    const int* ne    = (const int*)d_in[12];
    const int* comm  = (const int*)d_in[13];

    const int E = in_sizes[11] / 2;          // 800000
    const int n = in_sizes[0] / DFEAT;       // 50000

    float* out    = (float*)d_out;
    float* z      = out + 1;                             // [n,128]
    float* clar_f = out + 1 + (size_t)n * 128;           // [n]

    // workspace layout
    char*  w   = (char*)d_ws;
    size_t big = (size_t)n * DFEAT * sizeof(float);      // 12.8 MB
    float* a1    = (float*)(w);
    float* a2    = (float*)(w + big);
    float* h_pos = (float*)(w + 2 * big);
    float* h_neg = (float*)(w + 3 * big);
    char*  sm    = w + 4 * big;
    float* cntf_p = (float*)sm;            sm += (size_t)n * 4;
    float* cntf_n = (float*)sm;            sm += (size_t)n * 4;   // contiguous with cntf_p
    float* invn   = (float*)sm;            sm += (size_t)n * 4;
    float* scal   = (float*)sm;            sm += 64;              // [0]=lp_sum [1]=sim1 [2]=sim2
    int*   clar_i = (int*)sm;              sm += (size_t)n * 4;
    int*   cnt_i  = (int*)sm;              sm += 2 * (size_t)n * 4; // cnt_p | cnt_n contiguous
    int*   cnt_p  = cnt_i;
    int*   cnt_n  = cnt_i + n;

    const int* rp = pe,     *cp = pe + E;
    const int* rn = ne,     *cn = ne + E;

    const int egrid  = (E + 255) / 256;
    const int sgrid  = (E * 16 + 255) / 256;
    const int simg   = (E * 8 + 255) / 256;
    const int ngrid  = (n + 255) / 256;
    const int fgrid  = n / 4;                 // n % 4 == 0

    // zero accumulators (ws is poisoned each call)
    hipMemsetAsync(cnt_i, 0, 2 * (size_t)n * 4, stream);
    hipMemsetAsync(scal, 0, 64, stream);
    hipMemsetAsync(a1, 0, 2 * big, stream);

    // degree counts (shared by base + deep layers)
    count_edges_k<<<egrid, 256, 0, stream>>>(rp, E, cnt_p);
    count_edges_k<<<egrid, 256, 0, stream>>>(rn, E, cnt_n);
    make_cntf_k<<<(2 * n + 255) / 256, 256, 0, stream>>>(cnt_i, 2 * n, cntf_p);

    // ---- layer 0 (base) ----
    scatter_add_k<<<sgrid, 256, 0, stream>>>(X, rp, cp, E, a1);
    scatter_add_k<<<sgrid, 256, 0, stream>>>(X, rn, cn, E, a2);
    fused_linear_k<128, false><<<fgrid, 256, 0, stream>>>(a1, cntf_p, nullptr, nullptr, X, pbW, pbB, h_pos, 64);
    fused_linear_k<128, false><<<fgrid, 256, 0, stream>>>(a2, cntf_n, nullptr, nullptr, X, nbW, nbB, h_neg, 64);

    // ---- layer 1 (deep, pos): mean(h_pos|pos), mean(h_neg|neg), self=h_pos ----
    hipMemsetAsync(a1, 0, 2 * big, stream);
    scatter_add_k<<<sgrid, 256, 0, stream>>>(h_pos, rp, cp, E, a1);
    scatter_add_k<<<sgrid, 256, 0, stream>>>(h_neg, rn, cn, E, a2);
    fused_linear_k<192, true><<<fgrid, 256, 0, stream>>>(a1, cntf_p, a2, cntf_n, h_pos, pdW, pdB, z, 128);

    // ---- layer 1 (deep, neg): mean(h_neg|pos), mean(h_pos|neg), self=h_neg ----
    hipMemsetAsync(a1, 0, 2 * big, stream);
    scatter_add_k<<<sgrid, 256, 0, stream>>>(h_neg, rp, cp, E, a1);
    scatter_add_k<<<sgrid, 256, 0, stream>>>(h_pos, rn, cn, E, a2);
    fused_linear_k<192, true><<<fgrid, 256, 0, stream>>>(a1, cntf_p, a2, cntf_n, h_neg, ndW, ndB, z + 64, 128);

    // ---- losses ----
    logits_k<<<ngrid, 256, 0, stream>>>(z, rW, rB, comm, clar_f, clar_i, invn, &scal[0], n);
    sim_k<0><<<simg, 256, 0, stream>>>(z, invn, clar_i, rp, cp, E, &scal[1]);
    sim_k<1><<<simg, 256, 0, stream>>>(z, invn, clar_i, rn, cn, E, &scal[2]);
    finalize_k<<<1, 64, 0, stream>>>(scal, out, n, E);
}

// Round 4
// 1585.324 us; speedup vs baseline: 3.3415x; 3.3415x over previous
//
#include <hip/hip_runtime.h>
#include <hip/hip_bf16.h>
#include <math.h>

// Problem constants (from reference): N=50000, D=64, E=800000, H=64
#define DFEAT 64

// ---------------- count in-degree (int atomics, cheap) ----------------
__global__ void count_edges_k(const int* __restrict__ rows, int E, int* __restrict__ cnt) {
    int e = blockIdx.x * blockDim.x + threadIdx.x;
    if (e < E) atomicAdd(&cnt[rows[e]], 1);
}

// ---------------- exclusive scan of counts -> CSR offsets + cursor ----------------
// One block (1024 threads) per edge-type; n = 50000, per-thread chunk = 49.
__global__ __launch_bounds__(1024) void scan_k(const int* __restrict__ cnt_all, int n,
                                               int* __restrict__ offs_all, int* __restrict__ cur_all) {
    const int* cnt = cnt_all + (size_t)blockIdx.x * n;
    int* offs = offs_all + (size_t)blockIdx.x * (n + 1);
    int* cur  = cur_all  + (size_t)blockIdx.x * n;

    __shared__ int lsum[1024];
    int tid = threadIdx.x;
    int per = (n + 1023) / 1024;
    int start = tid * per;
    int s = 0;
    for (int j = 0; j < per; ++j) {
        int i = start + j;
        if (i < n) s += cnt[i];
    }
    lsum[tid] = s;
    __syncthreads();
    // Hillis-Steele inclusive scan
    for (int off = 1; off < 1024; off <<= 1) {
        int v = (tid >= off) ? lsum[tid - off] : 0;
        __syncthreads();
        lsum[tid] += v;
        __syncthreads();
    }
    int running = lsum[tid] - s;   // exclusive base for this thread
    for (int j = 0; j < per; ++j) {
        int i = start + j;
        if (i < n) {
            offs[i] = running;
            cur[i]  = running;
            running += cnt[i];
        }
    }
    if (tid == 1023) offs[n] = lsum[1023];
}

// ---------------- fill CSR col lists (int atomics for slot allocation) ----------------
__global__ void fill_k(const int* __restrict__ rows, const int* __restrict__ cols, int E,
                       int* __restrict__ cur, int* __restrict__ col_list) {
    int e = blockIdx.x * blockDim.x + threadIdx.x;
    if (e < E) {
        int r = rows[e];
        int p = atomicAdd(&cur[r], 1);
        col_list[p] = cols[e];
    }
}

// ---------------- CSR gather-mean: one wave per destination row ----------------
// lane = feature dim; each edge = one coalesced 256B read per source.
// DUAL gathers two source tables through the same col list.
template<bool DUAL>
__global__ __launch_bounds__(256) void gather_mean_k(
        const float* __restrict__ s1, const float* __restrict__ s2,
        const int* __restrict__ offs, const int* __restrict__ cols,
        float* __restrict__ o1, float* __restrict__ o2, int ostride, int n) {
    int gid  = (blockIdx.x * blockDim.x + threadIdx.x) >> 6;
    int lane = threadIdx.x & 63;
    if (gid >= n) return;
    int beg = offs[gid], end = offs[gid + 1];
    float a1 = 0.f, a2 = 0.f;
    int e = beg;
    for (; e + 1 < end; e += 2) {           // 2-edge unroll for ILP
        int c0 = cols[e], c1 = cols[e + 1];
        float v0 = s1[(size_t)c0 * DFEAT + lane];
        float v1 = s1[(size_t)c1 * DFEAT + lane];
        a1 += v0 + v1;
        if (DUAL) {
            float w0 = s2[(size_t)c0 * DFEAT + lane];
            float w1 = s2[(size_t)c1 * DFEAT + lane];
            a2 += w0 + w1;
        }
    }
    if (e < end) {
        int c0 = cols[e];
        a1 += s1[(size_t)c0 * DFEAT + lane];
        if (DUAL) a2 += s2[(size_t)c0 * DFEAT + lane];
    }
    int deg = end - beg;
    float inv = 1.f / (float)(deg > 1 ? deg : 1);
    o1[(size_t)gid * ostride + lane] = a1 * inv;
    if (DUAL) o2[(size_t)gid * ostride + lane] = a2 * inv;
}

// ---------------- fused: out = tanh(l2norm(concat @ W + b)) ----------------
// One wave per node row; lane = output column h (H=64 == wave size).
// W kept in natural [K,64] layout in LDS: Ws[k*64+lane] -> bank = lane%32,
// 2-way aliasing only (free). cat[wave][k] is a wave-broadcast (free).
template<int K, bool HAS2>
__global__ __launch_bounds__(256) void fused_linear_k(
        const float* __restrict__ p1, int s1,
        const float* __restrict__ p2, int s2,
        const float* __restrict__ p3, int s3,
        const float* __restrict__ W, const float* __restrict__ b,
        float* __restrict__ out, int os) {
    __shared__ float Ws[K * 64];
    __shared__ float bs[64];
    __shared__ float cat[4][K];

    for (int idx = threadIdx.x; idx < K * 64; idx += 256) Ws[idx] = W[idx];
    if (threadIdx.x < 64) bs[threadIdx.x] = b[threadIdx.x];

    int wave = threadIdx.x >> 6;
    int lane = threadIdx.x & 63;
    int row  = blockIdx.x * 4 + wave;      // grid sized exactly: n % 4 == 0

    cat[wave][lane] = p1[(size_t)row * s1 + lane];
    if (HAS2) {
        cat[wave][64 + lane]  = p2[(size_t)row * s2 + lane];
        cat[wave][128 + lane] = p3[(size_t)row * s3 + lane];
    } else {
        cat[wave][64 + lane]  = p3[(size_t)row * s3 + lane];
    }
    __syncthreads();

    float acc = 0.f;
    #pragma unroll
    for (int k = 0; k < K; k += 4) {
        float4 cv = *reinterpret_cast<const float4*>(&cat[wave][k]);  // broadcast
        acc = fmaf(cv.x, Ws[(k + 0) * 64 + lane], acc);
        acc = fmaf(cv.y, Ws[(k + 1) * 64 + lane], acc);
        acc = fmaf(cv.z, Ws[(k + 2) * 64 + lane], acc);
        acc = fmaf(cv.w, Ws[(k + 3) * 64 + lane], acc);
    }
    float v = acc + bs[lane];
    float ss = v * v;
    #pragma unroll
    for (int i = 1; i < 64; i <<= 1) ss += __shfl_xor(ss, i);
    float denom = fmaxf(sqrtf(ss), 1e-12f);
    out[(size_t)row * os + lane] = tanhf(v / denom);
}

// ---------------- logits + log_softmax + argmax + node norm ----------------
__global__ __launch_bounds__(256) void logits_k(
        const float* __restrict__ z, const float* __restrict__ Wr,
        const float* __restrict__ br, const int* __restrict__ comm,
        float* __restrict__ clar_f, int* __restrict__ clar_i,
        float* __restrict__ invn, float* __restrict__ lp_sum, int n) {
    __shared__ float Wl[128 * 3];
    for (int idx = threadIdx.x; idx < 384; idx += blockDim.x) Wl[idx] = Wr[idx];
    __syncthreads();
    int i = blockIdx.x * blockDim.x + threadIdx.x;
    float lp = 0.f;
    if (i < n) {
        float l0 = br[0], l1 = br[1], l2 = br[2], ss = 0.f;
        const float* zr = z + (size_t)i * 128;
        #pragma unroll 4
        for (int k = 0; k < 128; k += 4) {
            float4 v = *reinterpret_cast<const float4*>(zr + k);
            float zz[4] = {v.x, v.y, v.z, v.w};
            #pragma unroll
            for (int j = 0; j < 4; ++j) {
                float zv = zz[j];
                int kk = k + j;
                l0 = fmaf(zv, Wl[3 * kk + 0], l0);
                l1 = fmaf(zv, Wl[3 * kk + 1], l1);
                l2 = fmaf(zv, Wl[3 * kk + 2], l2);
                ss = fmaf(zv, zv, ss);
            }
        }
        invn[i] = 1.f / fmaxf(sqrtf(ss), 1e-8f);
        int idx = 0; float mv = l0;
        if (l1 > mv) { mv = l1; idx = 1; }
        if (l2 > mv) { mv = l2; idx = 2; }
        clar_i[i] = idx;
        clar_f[i] = (float)idx;
        float lse = mv + logf(expf(l0 - mv) + expf(l1 - mv) + expf(l2 - mv));
        int c = comm[i];
        lp = (c == 0 ? l0 : (c == 1 ? l1 : l2)) - lse;
    }
    #pragma unroll
    for (int o = 1; o < 64; o <<= 1) lp += __shfl_xor(lp, o);
    __shared__ float wsum[4];
    if ((threadIdx.x & 63) == 0) wsum[threadIdx.x >> 6] = lp;
    __syncthreads();
    if (threadIdx.x == 0) atomicAdd(lp_sum, wsum[0] + wsum[1] + wsum[2] + wsum[3]);
}

// ---------------- cosine-sim edge losses ----------------
// 8 lanes per edge; MODE 0: sum max(cos,0) where clarify differs (pos edges)
//                  MODE 1: sum -min(cos,0) where clarify equal (neg edges)
template<int MODE>
__global__ __launch_bounds__(256) void sim_k(
        const float* __restrict__ z, const float* __restrict__ invn,
        const int* __restrict__ clar, const int* __restrict__ ri,
        const int* __restrict__ ci, int E, float* __restrict__ osum) {
    int t = blockIdx.x * blockDim.x + threadIdx.x;
    int e = t >> 3;
    int sub = t & 7;
    float contrib = 0.f;
    if (e < E) {
        int a = ri[e], b = ci[e];
        const float* za = z + (size_t)a * 128 + sub * 16;
        const float* zb = z + (size_t)b * 128 + sub * 16;
        float d = 0.f;
        #pragma unroll
        for (int q = 0; q < 16; q += 4) {
            float4 x = *reinterpret_cast<const float4*>(za + q);
            float4 y = *reinterpret_cast<const float4*>(zb + q);
            d = fmaf(x.x, y.x, d);
            d = fmaf(x.y, y.y, d);
            d = fmaf(x.z, y.z, d);
            d = fmaf(x.w, y.w, d);
        }
        d += __shfl_xor(d, 1);
        d += __shfl_xor(d, 2);
        d += __shfl_xor(d, 4);
        if (sub == 0) {
            float cosv = d * invn[a] * invn[b];
            if (MODE == 0) { if (clar[a] != clar[b]) contrib = fmaxf(cosv, 0.f); }
            else           { if (clar[a] == clar[b]) contrib = -fminf(cosv, 0.f); }
        }
    }
    #pragma unroll
    for (int o = 1; o < 64; o <<= 1) contrib += __shfl_xor(contrib, o);
    __shared__ float wsum[4];
    if ((threadIdx.x & 63) == 0) wsum[threadIdx.x >> 6] = contrib;
    __syncthreads();
    if (threadIdx.x == 0) atomicAdd(osum, wsum[0] + wsum[1] + wsum[2] + wsum[3]);
}

__global__ void finalize_k(const float* __restrict__ scal, float* __restrict__ out,
                           int n, int E) {
    if (threadIdx.x == 0 && blockIdx.x == 0) {
        float reg_loss = -scal[0] / (float)n;
        float sim1 = scal[1] / (float)E;
        float sim2 = scal[2] / (float)E;
        out[0] = 0.8f * reg_loss + 0.2f * (sim1 + sim2);
    }
}

extern "C" void kernel_launch(void* const* d_in, const int* in_sizes, int n_in,
                              void* d_out, int out_size, void* d_ws, size_t ws_size,
                              hipStream_t stream) {
    const float* X   = (const float*)d_in[0];
    const float* pbW = (const float*)d_in[1];
    const float* pbB = (const float*)d_in[2];
    const float* nbW = (const float*)d_in[3];
    const float* nbB = (const float*)d_in[4];
    const float* pdW = (const float*)d_in[5];
    const float* pdB = (const float*)d_in[6];
    const float* ndW = (const float*)d_in[7];
    const float* ndB = (const float*)d_in[8];
    const float* rW  = (const float*)d_in[9];
    const float* rB  = (const float*)d_in[10];
    const int* pe    = (const int*)d_in[11];
    const int* ne    = (const int*)d_in[12];
    const int* comm  = (const int*)d_in[13];

    const int E = in_sizes[11] / 2;          // 800000
    const int n = in_sizes[0] / DFEAT;       // 50000

    float* out    = (float*)d_out;
    float* z      = out + 1;                             // [n,128]
    float* clar_f = out + 1 + (size_t)n * 128;           // [n]

    // workspace layout
    char*  w   = (char*)d_ws;
    size_t big = (size_t)n * DFEAT * sizeof(float);      // 12.8 MB
    float* a1    = (float*)(w);
    float* a2    = (float*)(w + big);
    float* h_pos = (float*)(w + 2 * big);
    float* h_neg = (float*)(w + 3 * big);
    char*  sm    = w + 4 * big;
    int* col_p  = (int*)sm;  sm += (size_t)E * 4;
    int* col_n  = (int*)sm;  sm += (size_t)E * 4;
    int* offs   = (int*)sm;  sm += 2 * (size_t)(n + 1) * 4;  // offs_p | offs_n
    int* cur    = (int*)sm;  sm += 2 * (size_t)n * 4;        // cur_p | cur_n
    int* cnt    = (int*)sm;  sm += 2 * (size_t)n * 4;        // cnt_p | cnt_n
    float* invn = (float*)sm; sm += (size_t)n * 4;
    int* clar_i = (int*)sm;  sm += (size_t)n * 4;
    float* scal = (float*)sm; sm += 64;   // [0]=lp_sum [1]=sim1 [2]=sim2

    int* offs_p = offs;
    int* offs_n = offs + (n + 1);
    int* cur_p  = cur;
    int* cur_n  = cur + n;
    int* cnt_p  = cnt;
    int* cnt_n  = cnt + n;

    const int* rp = pe, *cp = pe + E;
    const int* rn = ne, *cn = ne + E;

    const int egrid = (E + 255) / 256;
    const int simg  = (E * 8 + 255) / 256;
    const int ngrid = (n + 255) / 256;
    const int fgrid = n / 4;                 // n % 4 == 0 (12500)

    // zero only small accumulators (ws is poisoned each call)
    hipMemsetAsync(cnt, 0, 2 * (size_t)n * 4, stream);
    hipMemsetAsync(scal, 0, 64, stream);

    // ---- CSR build (pos & neg), reused by all 6 aggregations ----
    count_edges_k<<<egrid, 256, 0, stream>>>(rp, E, cnt_p);
    count_edges_k<<<egrid, 256, 0, stream>>>(rn, E, cnt_n);
    scan_k<<<2, 1024, 0, stream>>>(cnt, n, offs, cur);
    fill_k<<<egrid, 256, 0, stream>>>(rp, cp, E, cur_p, col_p);
    fill_k<<<egrid, 256, 0, stream>>>(rn, cn, E, cur_n, col_n);

    // ---- layer 0 (base) ----
    gather_mean_k<false><<<fgrid, 256, 0, stream>>>(X, nullptr, offs_p, col_p, a1, nullptr, 64, n);
    gather_mean_k<false><<<fgrid, 256, 0, stream>>>(X, nullptr, offs_n, col_n, a2, nullptr, 64, n);
    fused_linear_k<128, false><<<fgrid, 256, 0, stream>>>(a1, 64, nullptr, 0, X, 64, pbW, pbB, h_pos, 64);
    fused_linear_k<128, false><<<fgrid, 256, 0, stream>>>(a2, 64, nullptr, 0, X, 64, nbW, nbB, h_neg, 64);

    // ---- deep-layer aggregations (dual gathers share each CSR) ----
    // pos-CSR: gA = mean h_pos -> a1 (pos-deep in1), gB = mean h_neg -> a2 (neg-deep in1)
    gather_mean_k<true><<<fgrid, 256, 0, stream>>>(h_pos, h_neg, offs_p, col_p, a1, a2, 64, n);
    // neg-CSR: gC = mean h_neg -> z[:, :64] (pos-deep in2), gD = mean h_pos -> z[:, 64:] (neg-deep in2)
    gather_mean_k<true><<<fgrid, 256, 0, stream>>>(h_neg, h_pos, offs_n, col_n, z, z + 64, 128, n);

    // ---- deep linears (p2 in-place per-row with out: safe, per-row reads precede write) ----
    fused_linear_k<192, true><<<fgrid, 256, 0, stream>>>(a1, 64, z, 128, h_pos, 64, pdW, pdB, z, 128);
    fused_linear_k<192, true><<<fgrid, 256, 0, stream>>>(a2, 64, z + 64, 128, h_neg, 64, ndW, ndB, z + 64, 128);

    // ---- losses ----
    logits_k<<<ngrid, 256, 0, stream>>>(z, rW, rB, comm, clar_f, clar_i, invn, &scal[0], n);
    sim_k<0><<<simg, 256, 0, stream>>>(z, invn, clar_i, rp, cp, E, &scal[1]);
    sim_k<1><<<simg, 256, 0, stream>>>(z, invn, clar_i, rn, cn, E, &scal[2]);
    finalize_k<<<1, 64, 0, stream>>>(scal, out, n, E);
}

// Round 5
// 1299.937 us; speedup vs baseline: 4.0751x; 1.2195x over previous
//
#include <hip/hip_runtime.h>
#include <hip/hip_bf16.h>
#include <math.h>

// Problem constants (from reference): N=50000, D=64, E=800000, H=64
#define DFEAT 64

typedef unsigned int u32;
typedef unsigned short u16;

// bf16(hi 16 bits of f32) -> f32, exact
__device__ inline float bflo(u32 u) { return __uint_as_float(u << 16); }
__device__ inline float bfhi(u32 u) { return __uint_as_float(u & 0xffff0000u); }

// ---------------- count in-degree (int atomics, cheap) ----------------
__global__ void count_edges_k(const int* __restrict__ rows, int E, int* __restrict__ cnt) {
    int e = blockIdx.x * blockDim.x + threadIdx.x;
    if (e < E) atomicAdd(&cnt[rows[e]], 1);
}

// ---------------- exclusive scan of counts -> CSR offsets + cursor ----------------
__global__ __launch_bounds__(1024) void scan_k(const int* __restrict__ cnt_all, int n,
                                               int* __restrict__ offs_all, int* __restrict__ cur_all) {
    const int* cnt = cnt_all + (size_t)blockIdx.x * n;
    int* offs = offs_all + (size_t)blockIdx.x * (n + 1);
    int* cur  = cur_all  + (size_t)blockIdx.x * n;

    __shared__ int lsum[1024];
    int tid = threadIdx.x;
    int per = (n + 1023) / 1024;
    int start = tid * per;
    int s = 0;
    for (int j = 0; j < per; ++j) {
        int i = start + j;
        if (i < n) s += cnt[i];
    }
    lsum[tid] = s;
    __syncthreads();
    for (int off = 1; off < 1024; off <<= 1) {
        int v = (tid >= off) ? lsum[tid - off] : 0;
        __syncthreads();
        lsum[tid] += v;
        __syncthreads();
    }
    int running = lsum[tid] - s;
    for (int j = 0; j < per; ++j) {
        int i = start + j;
        if (i < n) {
            offs[i] = running;
            cur[i]  = running;
            running += cnt[i];
        }
    }
    if (tid == 1023) offs[n] = lsum[1023];
}

// ---------------- fill CSR col lists ----------------
__global__ void fill_k(const int* __restrict__ rows, const int* __restrict__ cols, int E,
                       int* __restrict__ cur, int* __restrict__ col_list) {
    int e = blockIdx.x * blockDim.x + threadIdx.x;
    if (e < E) {
        int r = rows[e];
        int p = atomicAdd(&cur[r], 1);
        col_list[p] = cols[e];
    }
}

// ---------------- CSR gather-mean from X (64-dim rows): wave per row ----------------
__global__ __launch_bounds__(256) void gather_mean_k(
        const float* __restrict__ s1,
        const int* __restrict__ offs, const int* __restrict__ cols,
        float* __restrict__ o1, int n) {
    int gid  = (blockIdx.x * blockDim.x + threadIdx.x) >> 6;
    int lane = threadIdx.x & 63;
    if (gid >= n) return;
    int beg = offs[gid], end = offs[gid + 1];
    float a = 0.f;
    int e = beg;
    for (; e + 1 < end; e += 2) {
        int c0 = cols[e], c1 = cols[e + 1];
        a += s1[(size_t)c0 * DFEAT + lane] + s1[(size_t)c1 * DFEAT + lane];
    }
    if (e < end) a += s1[(size_t)cols[e] * DFEAT + lane];
    int deg = end - beg;
    o1[(size_t)gid * DFEAT + lane] = a / (float)(deg > 1 ? deg : 1);
}

// ---------------- dual gather-mean from interleaved hcat[n][128] ----------------
// lane l holds dims 2l,2l+1 of the 128-dim row: lanes 0-31 = h_pos part -> o1,
// lanes 32-63 = h_neg part -> o2. One contiguous 512B read per edge.
__global__ __launch_bounds__(256) void dual_gather_k(
        const float* __restrict__ hcat,
        const int* __restrict__ offs, const int* __restrict__ cols,
        float* __restrict__ o1, int os1, float* __restrict__ o2, int os2, int n) {
    int gid  = (blockIdx.x * blockDim.x + threadIdx.x) >> 6;
    int lane = threadIdx.x & 63;
    if (gid >= n) return;
    int beg = offs[gid], end = offs[gid + 1];
    float sx = 0.f, sy = 0.f;
    int e = beg;
    for (; e + 1 < end; e += 2) {
        int c0 = cols[e], c1 = cols[e + 1];
        float2 v0 = *reinterpret_cast<const float2*>(hcat + (size_t)c0 * 128 + lane * 2);
        float2 v1 = *reinterpret_cast<const float2*>(hcat + (size_t)c1 * 128 + lane * 2);
        sx += v0.x + v1.x;
        sy += v0.y + v1.y;
    }
    if (e < end) {
        float2 v = *reinterpret_cast<const float2*>(hcat + (size_t)cols[e] * 128 + lane * 2);
        sx += v.x; sy += v.y;
    }
    int deg = end - beg;
    float inv = 1.f / (float)(deg > 1 ? deg : 1);
    sx *= inv; sy *= inv;
    if (lane < 32) {
        o1[(size_t)gid * os1 + lane * 2]     = sx;
        o1[(size_t)gid * os1 + lane * 2 + 1] = sy;
    } else {
        o2[(size_t)gid * os2 + (lane - 32) * 2]     = sx;
        o2[(size_t)gid * os2 + (lane - 32) * 2 + 1] = sy;
    }
}

// ---------------- fused: out = tanh(l2norm(concat @ W + b)) ----------------
template<int K, bool HAS2>
__global__ __launch_bounds__(256) void fused_linear_k(
        const float* __restrict__ p1, int s1,
        const float* __restrict__ p2, int s2,
        const float* __restrict__ p3, int s3,
        const float* __restrict__ W, const float* __restrict__ b,
        float* __restrict__ out, int os) {
    __shared__ float Ws[K * 64];
    __shared__ float bs[64];
    __shared__ float cat[4][K];

    for (int idx = threadIdx.x; idx < K * 64; idx += 256) Ws[idx] = W[idx];
    if (threadIdx.x < 64) bs[threadIdx.x] = b[threadIdx.x];

    int wave = threadIdx.x >> 6;
    int lane = threadIdx.x & 63;
    int row  = blockIdx.x * 4 + wave;      // grid sized exactly: n % 4 == 0

    cat[wave][lane] = p1[(size_t)row * s1 + lane];
    if (HAS2) {
        cat[wave][64 + lane]  = p2[(size_t)row * s2 + lane];
        cat[wave][128 + lane] = p3[(size_t)row * s3 + lane];
    } else {
        cat[wave][64 + lane]  = p3[(size_t)row * s3 + lane];
    }
    __syncthreads();

    float acc = 0.f;
    #pragma unroll
    for (int k = 0; k < K; k += 4) {
        float4 cv = *reinterpret_cast<const float4*>(&cat[wave][k]);  // broadcast
        acc = fmaf(cv.x, Ws[(k + 0) * 64 + lane], acc);
        acc = fmaf(cv.y, Ws[(k + 1) * 64 + lane], acc);
        acc = fmaf(cv.z, Ws[(k + 2) * 64 + lane], acc);
        acc = fmaf(cv.w, Ws[(k + 3) * 64 + lane], acc);
    }
    float v = acc + bs[lane];
    float ss = v * v;
    #pragma unroll
    for (int i = 1; i < 64; i <<= 1) ss += __shfl_xor(ss, i);
    float denom = fmaxf(sqrtf(ss), 1e-12f);
    out[(size_t)row * os + lane] = tanhf(v / denom);
}

// ---------------- normalize z rows -> bf16 table zn[n][128] ----------------
// wave per row; folds 1/max(||z||,1e-8) into the stored values so the sim
// kernels need only dot(zn[a], zn[b]).
__global__ __launch_bounds__(256) void normalize_k(
        const float* __restrict__ z, u16* __restrict__ zn, int n) {
    int gid  = (blockIdx.x * blockDim.x + threadIdx.x) >> 6;
    int lane = threadIdx.x & 63;
    if (gid >= n) return;
    float v0 = z[(size_t)gid * 128 + lane * 2];
    float v1 = z[(size_t)gid * 128 + lane * 2 + 1];
    float ss = v0 * v0 + v1 * v1;
    #pragma unroll
    for (int o = 1; o < 64; o <<= 1) ss += __shfl_xor(ss, o);
    float inv = 1.f / fmaxf(sqrtf(ss), 1e-8f);
    __hip_bfloat16 b0 = __float2bfloat16(v0 * inv);
    __hip_bfloat16 b1 = __float2bfloat16(v1 * inv);
    u16 s0 = *reinterpret_cast<u16*>(&b0);
    u16 s1 = *reinterpret_cast<u16*>(&b1);
    u32 packed = (u32)s0 | ((u32)s1 << 16);
    *reinterpret_cast<u32*>(zn + (size_t)gid * 128 + lane * 2) = packed;
}

// ---------------- logits + log_softmax + argmax ----------------
__global__ __launch_bounds__(256) void logits_k(
        const float* __restrict__ z, const float* __restrict__ Wr,
        const float* __restrict__ br, const int* __restrict__ comm,
        float* __restrict__ clar_f, int* __restrict__ clar_i,
        float* __restrict__ lp_sum, int n) {
    __shared__ float Wl[128 * 3];
    for (int idx = threadIdx.x; idx < 384; idx += blockDim.x) Wl[idx] = Wr[idx];
    __syncthreads();
    int i = blockIdx.x * blockDim.x + threadIdx.x;
    float lp = 0.f;
    if (i < n) {
        float l0 = br[0], l1 = br[1], l2 = br[2];
        const float* zr = z + (size_t)i * 128;
        #pragma unroll 4
        for (int k = 0; k < 128; k += 4) {
            float4 v = *reinterpret_cast<const float4*>(zr + k);
            float zz[4] = {v.x, v.y, v.z, v.w};
            #pragma unroll
            for (int j = 0; j < 4; ++j) {
                float zv = zz[j];
                int kk = k + j;
                l0 = fmaf(zv, Wl[3 * kk + 0], l0);
                l1 = fmaf(zv, Wl[3 * kk + 1], l1);
                l2 = fmaf(zv, Wl[3 * kk + 2], l2);
            }
        }
        int idx = 0; float mv = l0;
        if (l1 > mv) { mv = l1; idx = 1; }
        if (l2 > mv) { mv = l2; idx = 2; }
        clar_i[i] = idx;
        clar_f[i] = (float)idx;
        float lse = mv + logf(expf(l0 - mv) + expf(l1 - mv) + expf(l2 - mv));
        int c = comm[i];
        lp = (c == 0 ? l0 : (c == 1 ? l1 : l2)) - lse;
    }
    #pragma unroll
    for (int o = 1; o < 64; o <<= 1) lp += __shfl_xor(lp, o);
    __shared__ float wsum[4];
    if ((threadIdx.x & 63) == 0) wsum[threadIdx.x >> 6] = lp;
    __syncthreads();
    if (threadIdx.x == 0) atomicAdd(lp_sum, wsum[0] + wsum[1] + wsum[2] + wsum[3]);
}

// ---------------- CSR-grouped cosine-sim edge losses ----------------
// One wave per row a: zn[a] (bf16, pre-normalized) unpacked once into regs,
// reused over all neighbors. 16 lanes per edge (4 edges in flight per wave):
// lane sub=0..15 holds dims sub*8..sub*8+7. Per edge: one 16B load + 4-shfl reduce.
// MODE 0: sum max(cos,0) where clarify differs; MODE 1: sum -min(cos,0) where equal.
template<int MODE>
__global__ __launch_bounds__(256) void sim_csr_k(
        const u16* __restrict__ zn, const int* __restrict__ clar,
        const int* __restrict__ offs, const int* __restrict__ cols,
        float* __restrict__ osum, int n) {
    int gid  = (blockIdx.x * blockDim.x + threadIdx.x) >> 6;
    int lane = threadIdx.x & 63;
    int sub  = lane & 15;
    int q    = lane >> 4;
    float total = 0.f;
    if (gid < n) {
        uint4 ua = *reinterpret_cast<const uint4*>(zn + (size_t)gid * 128 + sub * 8);
        float a0 = bflo(ua.x), a1 = bfhi(ua.x), a2 = bflo(ua.y), a3 = bfhi(ua.y);
        float a4 = bflo(ua.z), a5 = bfhi(ua.z), a6 = bflo(ua.w), a7 = bfhi(ua.w);
        int ca = clar[gid];
        int beg = offs[gid], end = offs[gid + 1];
        for (int e = beg + q; e < end; e += 4) {
            int b = cols[e];
            uint4 ub = *reinterpret_cast<const uint4*>(zn + (size_t)b * 128 + sub * 8);
            float d;
            d = a0 * bflo(ub.x);
            d = fmaf(a1, bfhi(ub.x), d);
            d = fmaf(a2, bflo(ub.y), d);
            d = fmaf(a3, bfhi(ub.y), d);
            d = fmaf(a4, bflo(ub.z), d);
            d = fmaf(a5, bfhi(ub.z), d);
            d = fmaf(a6, bflo(ub.w), d);
            d = fmaf(a7, bfhi(ub.w), d);
            d += __shfl_xor(d, 1);
            d += __shfl_xor(d, 2);
            d += __shfl_xor(d, 4);
            d += __shfl_xor(d, 8);
            if (sub == 0) {
                int cb = clar[b];
                bool sel = (MODE == 0) ? (cb != ca) : (cb == ca);
                if (sel) total += (MODE == 0) ? fmaxf(d, 0.f) : -fminf(d, 0.f);
            }
        }
    }
    #pragma unroll
    for (int o = 1; o < 64; o <<= 1) total += __shfl_xor(total, o);
    __shared__ float wsum[4];
    if ((threadIdx.x & 63) == 0) wsum[threadIdx.x >> 6] = total;
    __syncthreads();
    if (threadIdx.x == 0) atomicAdd(osum, wsum[0] + wsum[1] + wsum[2] + wsum[3]);
}

__global__ void finalize_k(const float* __restrict__ scal, float* __restrict__ out,
                           int n, int E) {
    if (threadIdx.x == 0 && blockIdx.x == 0) {
        float reg_loss = -scal[0] / (float)n;
        float sim1 = scal[1] / (float)E;
        float sim2 = scal[2] / (float)E;
        out[0] = 0.8f * reg_loss + 0.2f * (sim1 + sim2);
    }
}

extern "C" void kernel_launch(void* const* d_in, const int* in_sizes, int n_in,
                              void* d_out, int out_size, void* d_ws, size_t ws_size,
                              hipStream_t stream) {
    const float* X   = (const float*)d_in[0];
    const float* pbW = (const float*)d_in[1];
    const float* pbB = (const float*)d_in[2];
    const float* nbW = (const float*)d_in[3];
    const float* nbB = (const float*)d_in[4];
    const float* pdW = (const float*)d_in[5];
    const float* pdB = (const float*)d_in[6];
    const float* ndW = (const float*)d_in[7];
    const float* ndB = (const float*)d_in[8];
    const float* rW  = (const float*)d_in[9];
    const float* rB  = (const float*)d_in[10];
    const int* pe    = (const int*)d_in[11];
    const int* ne    = (const int*)d_in[12];
    const int* comm  = (const int*)d_in[13];

    const int E = in_sizes[11] / 2;          // 800000
    const int n = in_sizes[0] / DFEAT;       // 50000

    float* out    = (float*)d_out;
    float* z      = out + 1;                             // [n,128]
    float* clar_f = out + 1 + (size_t)n * 128;           // [n]

    // workspace layout
    char*  w   = (char*)d_ws;
    size_t big = (size_t)n * DFEAT * sizeof(float);      // 12.8 MB
    float* a1    = (float*)(w);                          // [n,64]; reused as zn (bf16 [n,128]) after deep linears
    float* a2    = (float*)(w + big);                    // [n,64]
    float* hcat  = (float*)(w + 2 * big);                // [n,128] = h_pos | h_neg interleaved
    u16*   zn    = (u16*)a1;                             // n*128*2B == big exactly
    char*  sm    = w + 4 * big;
    int* col_p  = (int*)sm;  sm += (size_t)E * 4;
    int* col_n  = (int*)sm;  sm += (size_t)E * 4;
    int* offs   = (int*)sm;  sm += 2 * (size_t)(n + 1) * 4;  // offs_p | offs_n
    int* cur    = (int*)sm;  sm += 2 * (size_t)n * 4;        // cur_p | cur_n
    int* cnt    = (int*)sm;  sm += 2 * (size_t)n * 4;        // cnt_p | cnt_n
    int* clar_i = (int*)sm;  sm += (size_t)n * 4;
    float* scal = (float*)sm; sm += 64;   // [0]=lp_sum [1]=sim1 [2]=sim2

    int* offs_p = offs;
    int* offs_n = offs + (n + 1);
    int* cur_p  = cur;
    int* cur_n  = cur + n;
    int* cnt_p  = cnt;
    int* cnt_n  = cnt + n;

    const int* rp = pe, *cp = pe + E;
    const int* rn = ne, *cn = ne + E;

    const int egrid = (E + 255) / 256;
    const int ngrid = (n + 255) / 256;
    const int fgrid = n / 4;                 // n % 4 == 0 (12500)

    // zero only small accumulators (ws is poisoned each call)
    hipMemsetAsync(cnt, 0, 2 * (size_t)n * 4, stream);
    hipMemsetAsync(scal, 0, 64, stream);

    // ---- CSR build (pos & neg), reused by all aggregations + sims ----
    count_edges_k<<<egrid, 256, 0, stream>>>(rp, E, cnt_p);
    count_edges_k<<<egrid, 256, 0, stream>>>(rn, E, cnt_n);
    scan_k<<<2, 1024, 0, stream>>>(cnt, n, offs, cur);
    fill_k<<<egrid, 256, 0, stream>>>(rp, cp, E, cur_p, col_p);
    fill_k<<<egrid, 256, 0, stream>>>(rn, cn, E, cur_n, col_n);

    // ---- layer 0 (base) ----
    gather_mean_k<<<fgrid, 256, 0, stream>>>(X, offs_p, col_p, a1, n);
    gather_mean_k<<<fgrid, 256, 0, stream>>>(X, offs_n, col_n, a2, n);
    // h_pos -> hcat[:, 0:64], h_neg -> hcat[:, 64:128]
    fused_linear_k<128, false><<<fgrid, 256, 0, stream>>>(a1, 64, nullptr, 0, X, 64, pbW, pbB, hcat, 128);
    fused_linear_k<128, false><<<fgrid, 256, 0, stream>>>(a2, 64, nullptr, 0, X, 64, nbW, nbB, hcat + 64, 128);

    // ---- deep-layer aggregations: one 512B row read per edge via hcat ----
    // pos-CSR: gA = mean h_pos -> a1 (pos-deep in1), gB = mean h_neg -> a2 (neg-deep in1)
    dual_gather_k<<<fgrid, 256, 0, stream>>>(hcat, offs_p, col_p, a1, 64, a2, 64, n);
    // neg-CSR: gD = mean h_pos -> z[:,64:] (neg-deep in2), gC = mean h_neg -> z[:,:64] (pos-deep in2)
    dual_gather_k<<<fgrid, 256, 0, stream>>>(hcat, offs_n, col_n, z + 64, 128, z, 128, n);

    // ---- deep linears (p2 in-place per-row with out: safe, per-row reads precede write) ----
    fused_linear_k<192, true><<<fgrid, 256, 0, stream>>>(a1, 64, z, 128, hcat, 128, pdW, pdB, z, 128);
    fused_linear_k<192, true><<<fgrid, 256, 0, stream>>>(a2, 64, z + 64, 128, hcat + 64, 128, ndW, ndB, z + 64, 128);

    // ---- normalized bf16 z table (overwrites a1 — free now) ----
    normalize_k<<<fgrid, 256, 0, stream>>>(z, zn, n);

    // ---- losses ----
    logits_k<<<ngrid, 256, 0, stream>>>(z, rW, rB, comm, clar_f, clar_i, &scal[0], n);
    sim_csr_k<0><<<fgrid, 256, 0, stream>>>(zn, clar_i, offs_p, col_p, &scal[1], n);
    sim_csr_k<1><<<fgrid, 256, 0, stream>>>(zn, clar_i, offs_n, col_n, &scal[2], n);
    finalize_k<<<1, 64, 0, stream>>>(scal, out, n, E);
}

// Round 7
// 1252.602 us; speedup vs baseline: 4.2291x; 1.0378x over previous
//
#include <hip/hip_runtime.h>
#include <hip/hip_bf16.h>
#include <math.h>

// Problem constants (from reference): N=50000, D=64, E=800000, H=64
#define DFEAT 64

typedef unsigned int u32;
typedef unsigned short u16;

// bf16(hi 16 bits of f32) -> f32, exact
__device__ inline float bflo(u32 u) { return __uint_as_float(u << 16); }
__device__ inline float bfhi(u32 u) { return __uint_as_float(u & 0xffff0000u); }

// ---------------- count in-degree (int atomics, cheap) ----------------
__global__ void count_edges_k(const int* __restrict__ rows, int E, int* __restrict__ cnt) {
    int e = blockIdx.x * blockDim.x + threadIdx.x;
    if (e < E) atomicAdd(&cnt[rows[e]], 1);
}

// ---------------- exclusive scan of counts -> CSR offsets + cursor ----------------
__global__ __launch_bounds__(1024) void scan_k(const int* __restrict__ cnt_all, int n,
                                               int* __restrict__ offs_all, int* __restrict__ cur_all) {
    const int* cnt = cnt_all + (size_t)blockIdx.x * n;
    int* offs = offs_all + (size_t)blockIdx.x * (n + 1);
    int* cur  = cur_all  + (size_t)blockIdx.x * n;

    __shared__ int lsum[1024];
    int tid = threadIdx.x;
    int per = (n + 1023) / 1024;
    int start = tid * per;
    int s = 0;
    for (int j = 0; j < per; ++j) {
        int i = start + j;
        if (i < n) s += cnt[i];
    }
    lsum[tid] = s;
    __syncthreads();
    for (int off = 1; off < 1024; off <<= 1) {
        int v = (tid >= off) ? lsum[tid - off] : 0;
        __syncthreads();
        lsum[tid] += v;
        __syncthreads();
    }
    int running = lsum[tid] - s;
    for (int j = 0; j < per; ++j) {
        int i = start + j;
        if (i < n) {
            offs[i] = running;
            cur[i]  = running;
            running += cnt[i];
        }
    }
    if (tid == 1023) offs[n] = lsum[1023];
}

// ---------------- fill CSR col lists ----------------
__global__ void fill_k(const int* __restrict__ rows, const int* __restrict__ cols, int E,
                       int* __restrict__ cur, int* __restrict__ col_list) {
    int e = blockIdx.x * blockDim.x + threadIdx.x;
    if (e < E) {
        int r = rows[e];
        int p = atomicAdd(&cur[r], 1);
        col_list[p] = cols[e];
    }
}

// ---------------- fused pos+neg CSR gather-mean from X (blockIdx.y selects) ----------------
// wave per row, lane = dim; unroll 4 -> 4 independent row loads in flight.
__global__ __launch_bounds__(256) void gatherX_k(
        const float* __restrict__ X,
        const int* __restrict__ offs_p, const int* __restrict__ col_p,
        const int* __restrict__ offs_n, const int* __restrict__ col_n,
        float* __restrict__ a1, float* __restrict__ a2, int n) {
    int y = blockIdx.y;
    const int* offs = y ? offs_n : offs_p;
    const int* cols = y ? col_n : col_p;
    float* o = y ? a2 : a1;
    int gid  = (blockIdx.x * blockDim.x + threadIdx.x) >> 6;
    int lane = threadIdx.x & 63;
    if (gid >= n) return;
    int beg = offs[gid], end = offs[gid + 1];
    float a = 0.f;
    int e = beg;
    for (; e + 3 < end; e += 4) {
        int c0 = cols[e], c1 = cols[e + 1], c2 = cols[e + 2], c3 = cols[e + 3];
        float v0 = X[(size_t)c0 * DFEAT + lane];
        float v1 = X[(size_t)c1 * DFEAT + lane];
        float v2 = X[(size_t)c2 * DFEAT + lane];
        float v3 = X[(size_t)c3 * DFEAT + lane];
        a += (v0 + v1) + (v2 + v3);
    }
    for (; e < end; ++e) a += X[(size_t)cols[e] * DFEAT + lane];
    int deg = end - beg;
    o[(size_t)gid * DFEAT + lane] = a / (float)(deg > 1 ? deg : 1);
}

// ---------------- fused pos+neg dual gather-mean from hcat[n][128] ----------------
// lane l holds dims (2l, 2l+1); lanes 0-31 = h_pos half -> o1, lanes 32-63 = h_neg half -> o2.
// unroll 4 -> 4 independent 512B row loads in flight per wave.
__global__ __launch_bounds__(256) void dual_gather_k(
        const float* __restrict__ hcat,
        const int* __restrict__ offs_p, const int* __restrict__ col_p,
        const int* __restrict__ offs_n, const int* __restrict__ col_n,
        float* __restrict__ a1, float* __restrict__ a2,
        float* __restrict__ z, int n) {
    int y = blockIdx.y;
    const int* offs = y ? offs_n : offs_p;
    const int* cols = y ? col_n : col_p;
    float* o1 = y ? (z + 64) : a1;  int os1 = y ? 128 : 64;
    float* o2 = y ? z        : a2;  int os2 = y ? 128 : 64;

    int gid  = (blockIdx.x * blockDim.x + threadIdx.x) >> 6;
    int lane = threadIdx.x & 63;
    if (gid >= n) return;
    int beg = offs[gid], end = offs[gid + 1];
    float sx = 0.f, sy = 0.f;
    int e = beg;
    for (; e + 3 < end; e += 4) {
        int c0 = cols[e], c1 = cols[e + 1], c2 = cols[e + 2], c3 = cols[e + 3];
        float2 v0 = *reinterpret_cast<const float2*>(hcat + (size_t)c0 * 128 + lane * 2);
        float2 v1 = *reinterpret_cast<const float2*>(hcat + (size_t)c1 * 128 + lane * 2);
        float2 v2 = *reinterpret_cast<const float2*>(hcat + (size_t)c2 * 128 + lane * 2);
        float2 v3 = *reinterpret_cast<const float2*>(hcat + (size_t)c3 * 128 + lane * 2);
        sx += (v0.x + v1.x) + (v2.x + v3.x);
        sy += (v0.y + v1.y) + (v2.y + v3.y);
    }
    for (; e < end; ++e) {
        float2 v = *reinterpret_cast<const float2*>(hcat + (size_t)cols[e] * 128 + lane * 2);
        sx += v.x; sy += v.y;
    }
    int deg = end - beg;
    float inv = 1.f / (float)(deg > 1 ? deg : 1);
    sx *= inv; sy *= inv;
    if (lane < 32) {
        o1[(size_t)gid * os1 + lane * 2]     = sx;
        o1[(size_t)gid * os1 + lane * 2 + 1] = sy;
    } else {
        o2[(size_t)gid * os2 + (lane - 32) * 2]     = sx;
        o2[(size_t)gid * os2 + (lane - 32) * 2 + 1] = sy;
    }
}

// ---------------- fused: out = tanh(l2norm(concat @ W + b)) ----------------
template<int K, bool HAS2>
__global__ __launch_bounds__(256) void fused_linear_k(
        const float* __restrict__ p1, int s1,
        const float* __restrict__ p2, int s2,
        const float* __restrict__ p3, int s3,
        const float* __restrict__ W, const float* __restrict__ b,
        float* __restrict__ out, int os) {
    __shared__ float Ws[K * 64];
    __shared__ float bs[64];
    __shared__ float cat[4][K];

    for (int idx = threadIdx.x; idx < K * 64; idx += 256) Ws[idx] = W[idx];
    if (threadIdx.x < 64) bs[threadIdx.x] = b[threadIdx.x];

    int wave = threadIdx.x >> 6;
    int lane = threadIdx.x & 63;
    int row  = blockIdx.x * 4 + wave;      // grid sized exactly: n % 4 == 0

    cat[wave][lane] = p1[(size_t)row * s1 + lane];
    if (HAS2) {
        cat[wave][64 + lane]  = p2[(size_t)row * s2 + lane];
        cat[wave][128 + lane] = p3[(size_t)row * s3 + lane];
    } else {
        cat[wave][64 + lane]  = p3[(size_t)row * s3 + lane];
    }
    __syncthreads();

    float acc = 0.f;
    #pragma unroll
    for (int k = 0; k < K; k += 4) {
        float4 cv = *reinterpret_cast<const float4*>(&cat[wave][k]);  // broadcast
        acc = fmaf(cv.x, Ws[(k + 0) * 64 + lane], acc);
        acc = fmaf(cv.y, Ws[(k + 1) * 64 + lane], acc);
        acc = fmaf(cv.z, Ws[(k + 2) * 64 + lane], acc);
        acc = fmaf(cv.w, Ws[(k + 3) * 64 + lane], acc);
    }
    float v = acc + bs[lane];
    float ss = v * v;
    #pragma unroll
    for (int i = 1; i < 64; i <<= 1) ss += __shfl_xor(ss, i);
    float denom = fmaxf(sqrtf(ss), 1e-12f);
    out[(size_t)row * os + lane] = tanhf(v / denom);
}

// ---------------- normalize z rows -> bf16 table zn[n][128] ----------------
__global__ __launch_bounds__(256) void normalize_k(
        const float* __restrict__ z, u16* __restrict__ zn, int n) {
    int gid  = (blockIdx.x * blockDim.x + threadIdx.x) >> 6;
    int lane = threadIdx.x & 63;
    if (gid >= n) return;
    float v0 = z[(size_t)gid * 128 + lane * 2];
    float v1 = z[(size_t)gid * 128 + lane * 2 + 1];
    float ss = v0 * v0 + v1 * v1;
    #pragma unroll
    for (int o = 1; o < 64; o <<= 1) ss += __shfl_xor(ss, o);
    float inv = 1.f / fmaxf(sqrtf(ss), 1e-8f);
    __hip_bfloat16 b0 = __float2bfloat16(v0 * inv);
    __hip_bfloat16 b1 = __float2bfloat16(v1 * inv);
    u16 s0 = *reinterpret_cast<u16*>(&b0);
    u16 s1 = *reinterpret_cast<u16*>(&b1);
    u32 packed = (u32)s0 | ((u32)s1 << 16);
    *reinterpret_cast<u32*>(zn + (size_t)gid * 128 + lane * 2) = packed;
}

// ---------------- logits + log_softmax + argmax ----------------
__global__ __launch_bounds__(256) void logits_k(
        const float* __restrict__ z, const float* __restrict__ Wr,
        const float* __restrict__ br, const int* __restrict__ comm,
        float* __restrict__ clar_f, int* __restrict__ clar_i,
        float* __restrict__ lp_sum, int n) {
    __shared__ float Wl[128 * 3];
    for (int idx = threadIdx.x; idx < 384; idx += blockDim.x) Wl[idx] = Wr[idx];
    __syncthreads();
    int i = blockIdx.x * blockDim.x + threadIdx.x;
    float lp = 0.f;
    if (i < n) {
        float l0 = br[0], l1 = br[1], l2 = br[2];
        const float* zr = z + (size_t)i * 128;
        #pragma unroll 4
        for (int k = 0; k < 128; k += 4) {
            float4 v = *reinterpret_cast<const float4*>(zr + k);
            float zz[4] = {v.x, v.y, v.z, v.w};
            #pragma unroll
            for (int j = 0; j < 4; ++j) {
                float zv = zz[j];
                int kk = k + j;
                l0 = fmaf(zv, Wl[3 * kk + 0], l0);
                l1 = fmaf(zv, Wl[3 * kk + 1], l1);
                l2 = fmaf(zv, Wl[3 * kk + 2], l2);
            }
        }
        int idx = 0; float mv = l0;
        if (l1 > mv) { mv = l1; idx = 1; }
        if (l2 > mv) { mv = l2; idx = 2; }
        clar_i[i] = idx;
        clar_f[i] = (float)idx;
        float lse = mv + logf(expf(l0 - mv) + expf(l1 - mv) + expf(l2 - mv));
        int c = comm[i];
        lp = (c == 0 ? l0 : (c == 1 ? l1 : l2)) - lse;
    }
    #pragma unroll
    for (int o = 1; o < 64; o <<= 1) lp += __shfl_xor(lp, o);
    __shared__ float wsum[4];
    if ((threadIdx.x & 63) == 0) wsum[threadIdx.x >> 6] = lp;
    __syncthreads();
    if (threadIdx.x == 0) atomicAdd(lp_sum, wsum[0] + wsum[1] + wsum[2] + wsum[3]);
}

// ---------------- fused CSR-grouped cosine-sim losses (blockIdx.y = mode) ----------------
// One wave per row a: zn[a] (bf16 pre-normalized) in regs, reused over neighbors.
// 16 lanes per edge (4 edges in flight), clar pre-check skips unselected rows
// BEFORE loading the 256B zn row (mode0 keeps ~2/3, mode1 ~1/3).
__global__ __launch_bounds__(256) void sim_both_k(
        const u16* __restrict__ zn, const int* __restrict__ clar,
        const int* __restrict__ offs_p, const int* __restrict__ col_p,
        const int* __restrict__ offs_n, const int* __restrict__ col_n,
        float* __restrict__ scal, int n) {
    int mode = blockIdx.y;
    const int* offs = mode ? offs_n : offs_p;
    const int* cols = mode ? col_n : col_p;
    int gid  = (blockIdx.x * blockDim.x + threadIdx.x) >> 6;
    int lane = threadIdx.x & 63;
    int sub  = lane & 15;
    int q    = lane >> 4;
    float total = 0.f;
    if (gid < n) {
        uint4 ua = *reinterpret_cast<const uint4*>(zn + (size_t)gid * 128 + sub * 8);
        float a0 = bflo(ua.x), a1 = bfhi(ua.x), a2 = bflo(ua.y), a3 = bfhi(ua.y);
        float a4 = bflo(ua.z), a5 = bfhi(ua.z), a6 = bflo(ua.w), a7 = bfhi(ua.w);
        int ca = clar[gid];
        int beg = offs[gid], end = offs[gid + 1];
        #pragma unroll 2
        for (int e = beg + q; e < end; e += 4) {
            int b = cols[e];
            int cb = clar[b];                       // 4B broadcast within group (L2-hot 200KB)
            bool sel = mode ? (cb == ca) : (cb != ca);
            if (sel) {
                uint4 ub = *reinterpret_cast<const uint4*>(zn + (size_t)b * 128 + sub * 8);
                float d;
                d = a0 * bflo(ub.x);
                d = fmaf(a1, bfhi(ub.x), d);
                d = fmaf(a2, bflo(ub.y), d);
                d = fmaf(a3, bfhi(ub.y), d);
                d = fmaf(a4, bflo(ub.z), d);
                d = fmaf(a5, bfhi(ub.z), d);
                d = fmaf(a6, bflo(ub.w), d);
                d = fmaf(a7, bfhi(ub.w), d);
                d += __shfl_xor(d, 1);
                d += __shfl_xor(d, 2);
                d += __shfl_xor(d, 4);
                d += __shfl_xor(d, 8);
                if (sub == 0) total += mode ? -fminf(d, 0.f) : fmaxf(d, 0.f);
            }
        }
    }
    #pragma unroll
    for (int o = 1; o < 64; o <<= 1) total += __shfl_xor(total, o);
    __shared__ float wsum[4];
    if ((threadIdx.x & 63) == 0) wsum[threadIdx.x >> 6] = total;
    __syncthreads();
    if (threadIdx.x == 0) atomicAdd(&scal[1 + mode], wsum[0] + wsum[1] + wsum[2] + wsum[3]);
}

__global__ void finalize_k(const float* __restrict__ scal, float* __restrict__ out,
                           int n, int E) {
    if (threadIdx.x == 0 && blockIdx.x == 0) {
        float reg_loss = -scal[0] / (float)n;
        float sim1 = scal[1] / (float)E;
        float sim2 = scal[2] / (float)E;
        out[0] = 0.8f * reg_loss + 0.2f * (sim1 + sim2);
    }
}

extern "C" void kernel_launch(void* const* d_in, const int* in_sizes, int n_in,
                              void* d_out, int out_size, void* d_ws, size_t ws_size,
                              hipStream_t stream) {
    const float* X   = (const float*)d_in[0];
    const float* pbW = (const float*)d_in[1];
    const float* pbB = (const float*)d_in[2];
    const float* nbW = (const float*)d_in[3];
    const float* nbB = (const float*)d_in[4];
    const float* pdW = (const float*)d_in[5];
    const float* pdB = (const float*)d_in[6];
    const float* ndW = (const float*)d_in[7];
    const float* ndB = (const float*)d_in[8];
    const float* rW  = (const float*)d_in[9];
    const float* rB  = (const float*)d_in[10];
    const int* pe    = (const int*)d_in[11];
    const int* ne    = (const int*)d_in[12];
    const int* comm  = (const int*)d_in[13];

    const int E = in_sizes[11] / 2;          // 800000
    const int n = in_sizes[0] / DFEAT;       // 50000

    float* out    = (float*)d_out;
    float* z      = out + 1;                             // [n,128]
    float* clar_f = out + 1 + (size_t)n * 128;           // [n]

    // workspace layout
    char*  w   = (char*)d_ws;
    size_t big = (size_t)n * DFEAT * sizeof(float);      // 12.8 MB
    float* a1    = (float*)(w);                          // [n,64]; reused as zn (bf16 [n,128]) after deep linears
    float* a2    = (float*)(w + big);                    // [n,64]
    float* hcat  = (float*)(w + 2 * big);                // [n,128] = h_pos | h_neg
    u16*   zn    = (u16*)a1;                             // n*128*2B == big exactly
    char*  sm    = w + 4 * big;
    int* col_p  = (int*)sm;  sm += (size_t)E * 4;
    int* col_n  = (int*)sm;  sm += (size_t)E * 4;
    int* offs   = (int*)sm;  sm += 2 * (size_t)(n + 1) * 4;  // offs_p | offs_n
    int* cur    = (int*)sm;  sm += 2 * (size_t)n * 4;        // cur_p | cur_n
    int* cnt    = (int*)sm;  sm += 2 * (size_t)n * 4;        // cnt_p | cnt_n
    int* clar_i = (int*)sm;  sm += (size_t)n * 4;
    float* scal = (float*)sm; sm += 64;   // [0]=lp_sum [1]=sim1 [2]=sim2

    int* offs_p = offs;
    int* offs_n = offs + (n + 1);
    int* cur_p  = cur;
    int* cur_n  = cur + n;
    int* cnt_p  = cnt;
    int* cnt_n  = cnt + n;

    const int* rp = pe, *cp = pe + E;
    const int* rn = ne, *cn = ne + E;

    const int egrid = (E + 255) / 256;
    const int ngrid = (n + 255) / 256;
    const int fgrid = n / 4;                 // n % 4 == 0 (12500)

    // zero only small accumulators (ws is poisoned each call)
    hipMemsetAsync(cnt, 0, 2 * (size_t)n * 4, stream);
    hipMemsetAsync(scal, 0, 64, stream);

    // ---- CSR build (pos & neg), reused by all aggregations + sims ----
    count_edges_k<<<egrid, 256, 0, stream>>>(rp, E, cnt_p);
    count_edges_k<<<egrid, 256, 0, stream>>>(rn, E, cnt_n);
    scan_k<<<2, 1024, 0, stream>>>(cnt, n, offs, cur);
    fill_k<<<egrid, 256, 0, stream>>>(rp, cp, E, cur_p, col_p);
    fill_k<<<egrid, 256, 0, stream>>>(rn, cn, E, cur_n, col_n);

    // ---- layer 0 (base): both CSR gathers in one dispatch ----
    gatherX_k<<<dim3(fgrid, 2), 256, 0, stream>>>(X, offs_p, col_p, offs_n, col_n, a1, a2, n);
    // h_pos -> hcat[:, 0:64], h_neg -> hcat[:, 64:128]
    fused_linear_k<128, false><<<fgrid, 256, 0, stream>>>(a1, 64, nullptr, 0, X, 64, pbW, pbB, hcat, 128);
    fused_linear_k<128, false><<<fgrid, 256, 0, stream>>>(a2, 64, nullptr, 0, X, 64, nbW, nbB, hcat + 64, 128);

    // ---- deep-layer aggregations: both CSRs in one dispatch ----
    // y=0 (pos-CSR): mean h_pos -> a1, mean h_neg -> a2
    // y=1 (neg-CSR): mean h_pos -> z[:,64:], mean h_neg -> z[:,:64]
    dual_gather_k<<<dim3(fgrid, 2), 256, 0, stream>>>(hcat, offs_p, col_p, offs_n, col_n, a1, a2, z, n);

    // ---- deep linears (p2 in-place per-row with out: safe, per-row reads precede write) ----
    fused_linear_k<192, true><<<fgrid, 256, 0, stream>>>(a1, 64, z, 128, hcat, 128, pdW, pdB, z, 128);
    fused_linear_k<192, true><<<fgrid, 256, 0, stream>>>(a2, 64, z + 64, 128, hcat + 64, 128, ndW, ndB, z + 64, 128);

    // ---- normalized bf16 z table (overwrites a1 — free now) ----
    normalize_k<<<fgrid, 256, 0, stream>>>(z, zn, n);

    // ---- losses ----
    logits_k<<<ngrid, 256, 0, stream>>>(z, rW, rB, comm, clar_f, clar_i, &scal[0], n);
    sim_both_k<<<dim3(fgrid, 2), 256, 0, stream>>>(zn, clar_i, offs_p, col_p, offs_n, col_n, scal, n);
    finalize_k<<<1, 64, 0, stream>>>(scal, out, n, E);
}